// Round 4
// baseline (728.937 us; speedup 1.0000x reference)
//
#include <hip/hip_runtime.h>
#include <hip/hip_bf16.h>

#define B_  4
#define T_  256
#define U_  64
#define D_  512
#define INNER_ 512
#define VOCAB_ 2048

// ---------------- types ----------------
typedef __attribute__((ext_vector_type(8))) short short8;   // 8 bf16 (4 VGPRs)
typedef __attribute__((ext_vector_type(4))) float f32x4;

// ---------------- pass 1: projections (fp32) ----------------
__global__ __launch_bounds__(256) void proj_kernel(
    const float* __restrict__ enc, const float* __restrict__ dec,
    const float* __restrict__ W1, const float* __restrict__ b1,
    float* __restrict__ encP, float* __restrict__ decPb) {
  int ct = blockIdx.x;   // 0..3 col tiles of 128
  int rt = blockIdx.y;   // 0..79 row tiles of 16 (64 enc + 16 dec)
  const float* src; float* dst; int kOff; int addB1; int rowBase;
  if (rt < 64) { src = enc; dst = encP; kOff = 0; addB1 = 0; rowBase = rt * 16; }
  else { src = dec; dst = decPb; kOff = D_; addB1 = 1; rowBase = (rt - 64) * 16; }

  __shared__ float As[16][D_];  // 32 KiB
  int tid = threadIdx.x;
  const float4* s4 = (const float4*)(src + (size_t)rowBase * D_);
  float4* a4 = (float4*)(&As[0][0]);
#pragma unroll
  for (int i = 0; i < 8; i++) a4[tid + 256 * i] = s4[tid + 256 * i];
  __syncthreads();

  int colQ = (tid & 31) * 4;        // 4 consecutive cols within 128-tile
  int col = ct * 128 + colQ;
  int r0 = (tid >> 5) * 2;          // 2 rows
  float a00=0,a01=0,a02=0,a03=0, a10=0,a11=0,a12=0,a13=0;
  const float* Wp = W1 + (size_t)kOff * INNER_ + col;
#pragma unroll 4
  for (int k = 0; k < D_; k++) {
    float4 w = *(const float4*)(Wp + (size_t)k * INNER_);
    float e0 = As[r0][k], e1 = As[r0 + 1][k];
    a00 += e0 * w.x; a01 += e0 * w.y; a02 += e0 * w.z; a03 += e0 * w.w;
    a10 += e1 * w.x; a11 += e1 * w.y; a12 += e1 * w.z; a13 += e1 * w.w;
  }
  float4 bb = {0,0,0,0};
  if (addB1) bb = *(const float4*)(b1 + col);
  float4 o0 = {a00 + bb.x, a01 + bb.y, a02 + bb.z, a03 + bb.w};
  float4 o1 = {a10 + bb.x, a11 + bb.y, a12 + bb.z, a13 + bb.w};
  *(float4*)(dst + (size_t)(rowBase + r0) * INNER_ + col) = o0;
  *(float4*)(dst + (size_t)(rowBase + r0 + 1) * INNER_ + col) = o1;
}

// ---------------- pass 1b: W2 (512x2048 f32) -> W2T (2048x512 bf16) ----------------
__global__ __launch_bounds__(256) void w2t_kernel(
    const float* __restrict__ W2, __hip_bfloat16* __restrict__ W2T) {
  __shared__ float tile[32][33];
  int vBase = blockIdx.x * 32;  // 64
  int kBase = blockIdx.y * 32;  // 16
  int tx = threadIdx.x & 31, ty = threadIdx.x >> 5;  // 32 x 8
#pragma unroll
  for (int i = 0; i < 32; i += 8)
    tile[ty + i][tx] = W2[(size_t)(kBase + ty + i) * VOCAB_ + vBase + tx];
  __syncthreads();
#pragma unroll
  for (int i = 0; i < 32; i += 8)
    W2T[(size_t)(vBase + ty + i) * INNER_ + kBase + tx] = __float2bfloat16(tile[tx][ty + i]);
}

// ---------------- pass 2: hidden H[r][k] = tanh(encP[bt][k] + decPb[b*64+u][k]) ----------------
__global__ __launch_bounds__(256) void hidden_kernel(
    const float* __restrict__ encP, const float* __restrict__ decPb,
    __hip_bfloat16* __restrict__ H) {
  int gid = blockIdx.x * 256 + threadIdx.x;  // 4,194,304 total
  int k0 = (gid & 63) * 8;
  int r = gid >> 6;            // row in [0, 65536)
  int u = r & 63;
  int bt = r >> 6;             // b*T + t
  int b = bt >> 8;             // T = 256
  const float4* e = (const float4*)(encP + (size_t)bt * 512 + k0);
  const float4* dv = (const float4*)(decPb + (size_t)(b * 64 + u) * 512 + k0);
  float4 e0 = e[0], e1 = e[1];
  float4 d0 = dv[0], d1 = dv[1];
  union { __hip_bfloat16 h[8]; uint4 v; } p;
  p.h[0] = __float2bfloat16(tanhf(e0.x + d0.x));
  p.h[1] = __float2bfloat16(tanhf(e0.y + d0.y));
  p.h[2] = __float2bfloat16(tanhf(e0.z + d0.z));
  p.h[3] = __float2bfloat16(tanhf(e0.w + d0.w));
  p.h[4] = __float2bfloat16(tanhf(e1.x + d1.x));
  p.h[5] = __float2bfloat16(tanhf(e1.y + d1.y));
  p.h[6] = __float2bfloat16(tanhf(e1.z + d1.z));
  p.h[7] = __float2bfloat16(tanhf(e1.w + d1.w));
  *(uint4*)((__hip_bfloat16*)H + (size_t)r * 512 + k0) = p.v;
}

// ---------------- pass 3: main GEMM: out = H(65536x512) * W2T^T + b2 ----------------
// NEW this round: 256x128 tile, BK=32, 4 waves, 48 KiB LDS, <=256 VGPR
// => 2 blocks/CU so barrier stalls + epilogue overlap the sibling block's MFMA.
// Keeps T1 (XCD swizzle), T2 (XOR swizzle, both-sides), T4 (counted vmcnt),
// T5 (setprio), LDS-repack coalesced epilogue. Per-wave geometry unchanged
// (128x64 out, acc[8][4], 42.7 FLOP per LDS byte).
__device__ inline void gload_lds16(const void* g, void* l) {
  __builtin_amdgcn_global_load_lds(
      (const __attribute__((address_space(1))) unsigned int*)g,
      (__attribute__((address_space(3))) unsigned int*)l, 16, 0, 0);
}

__global__ __launch_bounds__(256, 2) void joint_gemm(
    const __hip_bfloat16* __restrict__ H, const __hip_bfloat16* __restrict__ W2T,
    const float* __restrict__ b2, float* __restrict__ out) {
  extern __shared__ char smem[];  // 48 KiB: A[2][256][32] bf16, B[2][128][32] bf16
  int tid = threadIdx.x;
  int lane = tid & 63, wave = tid >> 6;     // 4 waves
  int wm = wave >> 1, wn = wave & 1;        // 2x2 wave grid; per-wave 128x64 output

  // T1: XCD-aware bijective swizzle, nwg = 4096 (divisible by 8)
  int bid = blockIdx.x;
  int wg = (bid & 7) * 512 + (bid >> 3);
  int rt = wg >> 4;          // 0..255 (M tiles of 256)
  int ct = wg & 15;          // 0..15  (N tiles of 128)
  size_t rowBase = (size_t)rt * 256;
  int colBase = ct * 128;

  // ---- staging setup ----
  // Rows are 32 bf16 = 64 B = 4 x 16B chunks. Swizzle: chunk' = chunk ^ ((row>>1)&3).
  // LDS dest stays linear (global_load_lds rule); SOURCE is pre-swizzled (rule #21).
  // Thread: srow = tid>>2 (row within 64-row issue group), chunk = tid&3.
  int srow = tid >> 2;                                   // 0..63
  int kswz = ((tid & 3) ^ ((tid >> 3) & 3)) * 8;         // bf16 elem offset in 32-wide k
  const __hip_bfloat16* pA = H   + (rowBase + srow) * 512 + kswz;
  const __hip_bfloat16* pB = W2T + (size_t)(colBase + srow) * 512 + kswz;
  // LDS byte layout: A buf0 [0,16384) buf1 [16384,32768); B buf0 [32768,40960) buf1 [40960,49152)
  char* ldsA = smem;
  char* ldsB = smem + 32768;

  // Per STAGE: A = 256 rows = 4 issues of 64 rows; B = 128 rows = 2 issues. 6 loads/thread.
#define STAGE(t, buf) do {                                                    \
    const __hip_bfloat16* ga = pA + (size_t)(t) * 32;                         \
    const __hip_bfloat16* gb = pB + (size_t)(t) * 32;                         \
    char* la = ldsA + (buf) * 16384 + wave * 1024;                            \
    char* lb = ldsB + (buf) * 8192 + wave * 1024;                             \
    _Pragma("unroll")                                                         \
    for (int j = 0; j < 4; j++)                                               \
      gload_lds16(ga + (size_t)j * 64 * 512, la + j * 4096);                  \
    _Pragma("unroll")                                                         \
    for (int j = 0; j < 2; j++)                                               \
      gload_lds16(gb + (size_t)j * 64 * 512, lb + j * 4096);                  \
  } while (0)

  // ---- fragment ds_read offsets (swizzle-matched) ----
  // frag row r = base + (lane&15), k-group gs = lane>>4 (K=32 in one MFMA):
  // byte = r*64 + ((gs ^ ((r>>1)&3))*16).  base multiple of 16 -> (r>>1)&3 from lane only.
  int laneOff = (lane & 15) * 64 + (((lane >> 4) ^ (((lane & 15) >> 1) & 3)) * 16);
  int offA = wm * 8192 + laneOff;   // + mi*1024
  int offB = wn * 4096 + laneOff;   // + ni*1024

  // ---- acc init with bias ----
  float bv[4];
#pragma unroll
  for (int ni = 0; ni < 4; ni++) bv[ni] = b2[colBase + wn * 64 + ni * 16 + (lane & 15)];
  f32x4 acc[8][4];
#pragma unroll
  for (int mi = 0; mi < 8; mi++)
#pragma unroll
    for (int ni = 0; ni < 4; ni++)
      acc[mi][ni] = (f32x4){bv[ni], bv[ni], bv[ni], bv[ni]};

  // drain bias loads so vmcnt bookkeeping is exact
  asm volatile("s_waitcnt vmcnt(0)" ::: "memory");
  __builtin_amdgcn_sched_barrier(0);

  // prologue: tiles 0 and 1 in flight (6 loads each -> 12 outstanding)
  STAGE(0, 0);
  STAGE(1, 1);

  // Per K-tile: vmcnt(6)+barrier (tile t landed for all waves) -> ds_read 12 frags
  // -> lgkmcnt(0)+barrier (buf free) -> restage t+2 (loads fly during MFMA) ->
  // 32 MFMA. Tile t+1's loads stay in flight across everything (T4).
#define KITER(t, buf, VMC, DOSTAGE) do {                                      \
    asm volatile("s_waitcnt vmcnt(" #VMC ")" ::: "memory");                   \
    __builtin_amdgcn_sched_barrier(0);                                        \
    __builtin_amdgcn_s_barrier();                                             \
    __builtin_amdgcn_sched_barrier(0);                                        \
    const char* baA = ldsA + (buf) * 16384;                                   \
    const char* baB = ldsB + (buf) * 8192;                                    \
    short8 afr[8], bfr[4];                                                    \
    _Pragma("unroll") for (int ni = 0; ni < 4; ni++)                          \
      bfr[ni] = *(const short8*)(baB + offB + ni * 1024);                     \
    _Pragma("unroll") for (int mi = 0; mi < 8; mi++)                          \
      afr[mi] = *(const short8*)(baA + offA + mi * 1024);                     \
    asm volatile("s_waitcnt lgkmcnt(0)" ::: "memory");                        \
    __builtin_amdgcn_sched_barrier(0);                                        \
    __builtin_amdgcn_s_barrier();                                             \
    __builtin_amdgcn_sched_barrier(0);                                        \
    if (DOSTAGE) { STAGE((t) + 2, (buf)); }                                   \
    __builtin_amdgcn_sched_barrier(0);                                        \
    __builtin_amdgcn_s_setprio(1);                                            \
    _Pragma("unroll") for (int mi = 0; mi < 8; mi++)                          \
      _Pragma("unroll") for (int ni = 0; ni < 4; ni++)                        \
        acc[mi][ni] = __builtin_amdgcn_mfma_f32_16x16x32_bf16(                \
            afr[mi], bfr[ni], acc[mi][ni], 0, 0, 0);                          \
    __builtin_amdgcn_s_setprio(0);                                            \
  } while (0)

#pragma unroll 2
  for (int t = 0; t < 14; ++t) KITER(t, (t & 1), 6, 1);
  KITER(14, 0, 6, 0);
  KITER(15, 1, 0, 0);
#undef KITER
#undef STAGE

  // ---- epilogue: LDS repack -> coalesced 512B-run dwordx4 stores ----
  // 4 rounds of a 64x128 f32 panel (stride 132 dwords, 16B-aligned rows).
  // Round r = tile rows [r*64, +64): waves with wm==r>>1 write acc[(r&1)*4 .. +3][*],
  // then all 256 threads stream the panel out (32 lanes = one full 512 B row).
  {
    float* lp = (float*)smem;
    float* outBase = out + rowBase * VOCAB_ + colBase;
#pragma unroll
    for (int r = 0; r < 4; r++) {
      __syncthreads();                       // prev round's reads complete
      if (wm == (r >> 1)) {
        int mih = (r & 1) * 4;
#pragma unroll
        for (int q = 0; q < 4; q++) {
          int lrow0 = q * 16 + ((lane >> 4) << 2);
#pragma unroll
          for (int ni = 0; ni < 4; ni++) {
            int col = wn * 64 + ni * 16 + (lane & 15);
            f32x4 v = acc[mih + q][ni];
#pragma unroll
            for (int j = 0; j < 4; j++)
              lp[(lrow0 + j) * 132 + col] = v[j];
          }
        }
      }
      __syncthreads();                       // panel ready
#pragma unroll
      for (int i = 0; i < 8; i++) {
        int c = tid + 256 * i;               // [0,2048): row = c>>5, chunk = c&31
        int row = c >> 5, cc = c & 31;
        f32x4 v = *(const f32x4*)(lp + row * 132 + cc * 4);
        *(float4*)(outBase + (size_t)(r * 64 + row) * VOCAB_ + cc * 4) =
            (float4){v[0], v[1], v[2], v[3]};
      }
    }
  }
}

extern "C" void kernel_launch(void* const* d_in, const int* in_sizes, int n_in,
                              void* d_out, int out_size, void* d_ws, size_t ws_size,
                              hipStream_t stream) {
  const float* enc = (const float*)d_in[0];
  const float* dec = (const float*)d_in[1];
  const float* W1  = (const float*)d_in[2];
  const float* b1  = (const float*)d_in[3];
  const float* W2  = (const float*)d_in[4];
  const float* b2  = (const float*)d_in[5];
  float* out = (float*)d_out;

  char* ws = (char*)d_ws;
  float* encP  = (float*)ws;                                   // 1024*512*4 = 2 MiB
  float* decPb = (float*)(ws + (2u << 20));                    // 256*512*4 = 512 KiB
  __hip_bfloat16* W2T = (__hip_bfloat16*)(ws + (2u << 20) + (512u << 10));          // 2 MiB
  __hip_bfloat16* H   = (__hip_bfloat16*)(ws + (2u << 20) + (512u << 10) + (2u << 20)); // 64 MiB

  static int smem_set = 0;
  if (!smem_set) {
    (void)hipFuncSetAttribute((const void*)joint_gemm,
                              hipFuncAttributeMaxDynamicSharedMemorySize, 49152);
    smem_set = 1;
  }

  proj_kernel<<<dim3(4, 80), 256, 0, stream>>>(enc, dec, W1, b1, encP, decPb);
  w2t_kernel<<<dim3(64, 16), 256, 0, stream>>>(W2, W2T);
  hidden_kernel<<<16384, 256, 0, stream>>>(encP, decPb, H);
  joint_gemm<<<dim3(4096), 256, 49152, stream>>>(H, W2T, b2, out);
}

// Round 6
// 697.168 us; speedup vs baseline: 1.0456x; 1.0456x over previous
//
#include <hip/hip_runtime.h>
#include <hip/hip_bf16.h>

#define B_  4
#define T_  256
#define U_  64
#define D_  512
#define INNER_ 512
#define VOCAB_ 2048

// ---------------- types ----------------
typedef __attribute__((ext_vector_type(8))) short short8;   // 8 bf16 (4 VGPRs)
typedef __attribute__((ext_vector_type(4))) float f32x4;

// ---------------- pass 1 (merged): projections + W2 transpose ----------------
// blocks [0,320): proj; blocks [320,1344): w2t. Disjoint data, one dispatch.
__global__ __launch_bounds__(256) void prep_kernel(
    const float* __restrict__ enc, const float* __restrict__ dec,
    const float* __restrict__ W1, const float* __restrict__ b1,
    const float* __restrict__ W2,
    float* __restrict__ encP, float* __restrict__ decPb,
    __hip_bfloat16* __restrict__ W2T) {
  __shared__ float ldsbuf[16 * D_];  // 32 KiB (proj) / reused 32x33 (w2t)
  int tid = threadIdx.x;
  int bidx = blockIdx.x;

  if (bidx < 320) {
    // ---- proj ----
    int ct = bidx & 3;          // 0..3 col tiles of 128
    int rt = bidx >> 2;         // 0..79 row tiles of 16 (64 enc + 16 dec)
    const float* src; float* dst; int kOff; int addB1; int rowBase;
    if (rt < 64) { src = enc; dst = encP; kOff = 0; addB1 = 0; rowBase = rt * 16; }
    else { src = dec; dst = decPb; kOff = D_; addB1 = 1; rowBase = (rt - 64) * 16; }

    float (*As)[D_] = (float(*)[D_])ldsbuf;
    const float4* s4 = (const float4*)(src + (size_t)rowBase * D_);
    float4* a4 = (float4*)(&As[0][0]);
#pragma unroll
    for (int i = 0; i < 8; i++) a4[tid + 256 * i] = s4[tid + 256 * i];
    __syncthreads();

    int colQ = (tid & 31) * 4;
    int col = ct * 128 + colQ;
    int r0 = (tid >> 5) * 2;
    float a00=0,a01=0,a02=0,a03=0, a10=0,a11=0,a12=0,a13=0;
    const float* Wp = W1 + (size_t)kOff * INNER_ + col;
#pragma unroll 4
    for (int k = 0; k < D_; k++) {
      float4 w = *(const float4*)(Wp + (size_t)k * INNER_);
      float e0 = As[r0][k], e1 = As[r0 + 1][k];
      a00 += e0 * w.x; a01 += e0 * w.y; a02 += e0 * w.z; a03 += e0 * w.w;
      a10 += e1 * w.x; a11 += e1 * w.y; a12 += e1 * w.z; a13 += e1 * w.w;
    }
    float4 bb = {0,0,0,0};
    if (addB1) bb = *(const float4*)(b1 + col);
    float4 o0 = {a00 + bb.x, a01 + bb.y, a02 + bb.z, a03 + bb.w};
    float4 o1 = {a10 + bb.x, a11 + bb.y, a12 + bb.z, a13 + bb.w};
    *(float4*)(dst + (size_t)(rowBase + r0) * INNER_ + col) = o0;
    *(float4*)(dst + (size_t)(rowBase + r0 + 1) * INNER_ + col) = o1;
  } else {
    // ---- w2t: W2 (512x2048 f32) -> W2T (2048x512 bf16) ----
    int b = bidx - 320;               // 0..1023
    int vBase = (b & 63) * 32;
    int kBase = (b >> 6) * 32;
    float (*tile)[33] = (float(*)[33])ldsbuf;  // 4.2 KiB
    int tx = tid & 31, ty = tid >> 5; // 32 x 8
#pragma unroll
    for (int i = 0; i < 32; i += 8)
      tile[ty + i][tx] = W2[(size_t)(kBase + ty + i) * VOCAB_ + vBase + tx];
    __syncthreads();
#pragma unroll
    for (int i = 0; i < 32; i += 8)
      W2T[(size_t)(vBase + ty + i) * INNER_ + kBase + tx] = __float2bfloat16(tile[tx][ty + i]);
  }
}

// ---------------- pass 2: hidden H[r][k] = tanh(encP[bt][k] + decPb[b*64+u][k]) ----------------
__global__ __launch_bounds__(256) void hidden_kernel(
    const float* __restrict__ encP, const float* __restrict__ decPb,
    __hip_bfloat16* __restrict__ H) {
  int gid = blockIdx.x * 256 + threadIdx.x;  // 4,194,304 total
  int k0 = (gid & 63) * 8;
  int r = gid >> 6;            // row in [0, 65536)
  int u = r & 63;
  int bt = r >> 6;             // b*T + t
  int b = bt >> 8;             // T = 256
  const float4* e = (const float4*)(encP + (size_t)bt * 512 + k0);
  const float4* dv = (const float4*)(decPb + (size_t)(b * 64 + u) * 512 + k0);
  float4 e0 = e[0], e1 = e[1];
  float4 d0 = dv[0], d1 = dv[1];
  union { __hip_bfloat16 h[8]; uint4 v; } p;
  p.h[0] = __float2bfloat16(tanhf(e0.x + d0.x));
  p.h[1] = __float2bfloat16(tanhf(e0.y + d0.y));
  p.h[2] = __float2bfloat16(tanhf(e0.z + d0.z));
  p.h[3] = __float2bfloat16(tanhf(e0.w + d0.w));
  p.h[4] = __float2bfloat16(tanhf(e1.x + d1.x));
  p.h[5] = __float2bfloat16(tanhf(e1.y + d1.y));
  p.h[6] = __float2bfloat16(tanhf(e1.z + d1.z));
  p.h[7] = __float2bfloat16(tanhf(e1.w + d1.w));
  *(uint4*)((__hip_bfloat16*)H + (size_t)r * 512 + k0) = p.v;
}

// ---------------- pass 3: main GEMM: out = H(65536x512) * W2T^T + b2 ----------------
// 256x256 tile (halves H re-reads vs 256x128: 8 N-passes instead of 16),
// BK=32, 8 waves (2x4), 64 KiB K-loop LDS, counted vmcnt (T4), both-sides XOR
// swizzle (T2), setprio (T5), bijective XCD swizzle (T1), LDS-repack epilogue
// with NON-TEMPORAL stores (output written once, never read -> keep L2 for H/W2T).
__device__ inline void gload_lds16(const void* g, void* l) {
  __builtin_amdgcn_global_load_lds(
      (const __attribute__((address_space(1))) unsigned int*)g,
      (__attribute__((address_space(3))) unsigned int*)l, 16, 0, 0);
}

__global__ __launch_bounds__(512, 1) void joint_gemm(
    const __hip_bfloat16* __restrict__ H, const __hip_bfloat16* __restrict__ W2T,
    const float* __restrict__ b2, float* __restrict__ out) {
  extern __shared__ char smem[];  // 65 KiB: A[2][256][32] bf16 | B[2][256][32] bf16; epi panel 66560 B
  int tid = threadIdx.x;
  int lane = tid & 63, wave = tid >> 6;     // 8 waves
  int wm = wave >> 2, wn = wave & 3;        // 2x4 wave grid; per-wave 128x64 output

  // T1: XCD-aware bijective swizzle, nwg = 2048 (divisible by 8)
  int bid = blockIdx.x;
  int wg = (bid & 7) * 256 + (bid >> 3);
  int rt = wg >> 3;          // 0..255 (M tiles of 256)
  int ct = wg & 7;           // 0..7   (N tiles of 256)
  size_t rowBase = (size_t)rt * 256;
  int colBase = ct * 256;

  // ---- staging setup ----
  // Rows are 32 bf16 = 64 B = 4 chunks of 16 B. Swizzle chunk' = chunk ^ ((row>>1)&3).
  // LDS dest linear (global_load_lds rule); SOURCE pre-swizzled (rule #21).
  // Thread covers row wave*16 + (lane>>2) (+ j*128), chunk lane&3.
  // (row>>1)&3 == (lane>>3)&3 for all j,t (wave*16, j*128 don't touch bits 1-2).
  int kswz = ((lane & 3) ^ ((lane >> 3) & 3)) * 8;   // bf16 elem offset in 32-wide k
  int srow = wave * 16 + (lane >> 2);                // 0..127 staging row
  const __hip_bfloat16* pA = H   + (rowBase + srow) * 512 + kswz;
  const __hip_bfloat16* pB = W2T + (size_t)(colBase + srow) * 512 + kswz;
  char* ldsA = smem;             // [0, 32768): 2 bufs x 16 KiB
  char* ldsB = smem + 32768;     // [32768, 65536)

  // Per STAGE: A 256 rows = 2 issues of 128 rows; B same. 4 loads/thread.
#define STAGE(t, buf) do {                                                    \
    const __hip_bfloat16* ga = pA + (size_t)(t) * 32;                         \
    const __hip_bfloat16* gb = pB + (size_t)(t) * 32;                         \
    char* la = ldsA + (buf) * 16384 + wave * 1024;                            \
    char* lb = ldsB + (buf) * 16384 + wave * 1024;                            \
    gload_lds16(ga,                 la);                                      \
    gload_lds16(ga + 128 * 512,     la + 8192);                               \
    gload_lds16(gb,                 lb);                                      \
    gload_lds16(gb + 128 * 512,     lb + 8192);                               \
  } while (0)

  // ---- fragment ds_read offsets (swizzle-matched) ----
  // frag row r = base16 + (lane&15), k-group gs = lane>>4:
  // byte = r*64 + ((gs ^ ((r>>1)&3))*16); base16 mult of 16 -> swz from lane only.
  int laneOff = (lane & 15) * 64 + (((lane >> 4) ^ (((lane & 15) >> 1) & 3)) * 16);
  int offA = wm * 8192 + laneOff;   // + mi*1024, mi=0..7 (128 rows)
  int offB = wn * 4096 + laneOff;   // + ni*1024, ni=0..3 (64 rows)

  // ---- acc init with bias ----
  float bv[4];
#pragma unroll
  for (int ni = 0; ni < 4; ni++) bv[ni] = b2[colBase + wn * 64 + ni * 16 + (lane & 15)];
  f32x4 acc[8][4];
#pragma unroll
  for (int mi = 0; mi < 8; mi++)
#pragma unroll
    for (int ni = 0; ni < 4; ni++)
      acc[mi][ni] = (f32x4){bv[ni], bv[ni], bv[ni], bv[ni]};

  // drain bias loads so vmcnt bookkeeping is exact
  asm volatile("s_waitcnt vmcnt(0)" ::: "memory");
  __builtin_amdgcn_sched_barrier(0);

  // prologue: tiles 0 and 1 in flight (4 loads each -> 8 outstanding)
  STAGE(0, 0);
  STAGE(1, 1);

  // Per K-tile: vmcnt(4)+barrier (tile t landed) -> ds_read 12 frags ->
  // lgkmcnt(0)+barrier (buf free) -> restage t+2 (flies during MFMA) -> 32 MFMA.
  // Tile t+1's loads stay in flight across everything (T4).
#define KITER(t, buf, VMC, DOSTAGE) do {                                      \
    asm volatile("s_waitcnt vmcnt(" #VMC ")" ::: "memory");                   \
    __builtin_amdgcn_sched_barrier(0);                                        \
    __builtin_amdgcn_s_barrier();                                             \
    __builtin_amdgcn_sched_barrier(0);                                        \
    const char* baA = ldsA + (buf) * 16384;                                   \
    const char* baB = ldsB + (buf) * 16384;                                   \
    short8 afr[8], bfr[4];                                                    \
    _Pragma("unroll") for (int ni = 0; ni < 4; ni++)                          \
      bfr[ni] = *(const short8*)(baB + offB + ni * 1024);                     \
    _Pragma("unroll") for (int mi = 0; mi < 8; mi++)                          \
      afr[mi] = *(const short8*)(baA + offA + mi * 1024);                     \
    asm volatile("s_waitcnt lgkmcnt(0)" ::: "memory");                        \
    __builtin_amdgcn_sched_barrier(0);                                        \
    __builtin_amdgcn_s_barrier();                                             \
    __builtin_amdgcn_sched_barrier(0);                                        \
    if (DOSTAGE) { STAGE((t) + 2, (buf)); }                                   \
    __builtin_amdgcn_sched_barrier(0);                                        \
    __builtin_amdgcn_s_setprio(1);                                            \
    _Pragma("unroll") for (int mi = 0; mi < 8; mi++)                          \
      _Pragma("unroll") for (int ni = 0; ni < 4; ni++)                        \
        acc[mi][ni] = __builtin_amdgcn_mfma_f32_16x16x32_bf16(                \
            afr[mi], bfr[ni], acc[mi][ni], 0, 0, 0);                          \
    __builtin_amdgcn_s_setprio(0);                                            \
  } while (0)

#pragma unroll 2
  for (int t = 0; t < 14; ++t) KITER(t, (t & 1), 4, 1);
  KITER(14, 0, 4, 0);
  KITER(15, 1, 0, 0);
#undef KITER
#undef STAGE

  // ---- epilogue: LDS repack -> coalesced 1 KiB/wave NON-TEMPORAL dwordx4 stores ----
  // 4 rounds of a 64x256 f32 panel (stride 260 dwords: 16B-aligned rows, 2-way banks).
  // Round r = tile rows [r*64,+64): waves with wm==r>>1 write acc[(r&1)*4..+3][*];
  // then all 512 threads stream the panel (64 lanes x 16 B = one 1 KiB row).
  // NT store uses clang ext_vector f32x4 (HIP float4 class is rejected by the builtin).
  {
    float* lp = (float*)smem;
    float* outBase = out + rowBase * VOCAB_ + colBase;
#pragma unroll
    for (int r = 0; r < 4; r++) {
      __syncthreads();                       // prev round's reads complete
      if (wm == (r >> 1)) {
        int mih = (r & 1) * 4;
#pragma unroll
        for (int q = 0; q < 4; q++) {
          int lrow0 = q * 16 + ((lane >> 4) << 2);
#pragma unroll
          for (int ni = 0; ni < 4; ni++) {
            int col = wn * 64 + ni * 16 + (lane & 15);
            f32x4 v = acc[mih + q][ni];
#pragma unroll
            for (int j = 0; j < 4; j++)
              lp[(lrow0 + j) * 260 + col] = v[j];
          }
        }
      }
      __syncthreads();                       // panel ready
#pragma unroll
      for (int i = 0; i < 8; i++) {
        int c = tid + 512 * i;               // [0,4096): row = c>>6, chunk = c&63
        int row = c >> 6, cc = c & 63;
        f32x4 v = *(const f32x4*)(lp + row * 260 + cc * 4);
        __builtin_nontemporal_store(
            v, (f32x4*)(outBase + (size_t)(r * 64 + row) * VOCAB_ + cc * 4));
      }
    }
  }
}

extern "C" void kernel_launch(void* const* d_in, const int* in_sizes, int n_in,
                              void* d_out, int out_size, void* d_ws, size_t ws_size,
                              hipStream_t stream) {
  const float* enc = (const float*)d_in[0];
  const float* dec = (const float*)d_in[1];
  const float* W1  = (const float*)d_in[2];
  const float* b1  = (const float*)d_in[3];
  const float* W2  = (const float*)d_in[4];
  const float* b2  = (const float*)d_in[5];
  float* out = (float*)d_out;

  char* ws = (char*)d_ws;
  float* encP  = (float*)ws;                                   // 1024*512*4 = 2 MiB
  float* decPb = (float*)(ws + (2u << 20));                    // 256*512*4 = 512 KiB
  __hip_bfloat16* W2T = (__hip_bfloat16*)(ws + (2u << 20) + (512u << 10));          // 2 MiB
  __hip_bfloat16* H   = (__hip_bfloat16*)(ws + (2u << 20) + (512u << 10) + (2u << 20)); // 64 MiB

  static int smem_set = 0;
  if (!smem_set) {
    (void)hipFuncSetAttribute((const void*)joint_gemm,
                              hipFuncAttributeMaxDynamicSharedMemorySize, 66560);
    smem_set = 1;
  }

  prep_kernel<<<dim3(1344), 256, 0, stream>>>(enc, dec, W1, b1, W2, encP, decPb, W2T);
  hidden_kernel<<<16384, 256, 0, stream>>>(encP, decPb, H);
  joint_gemm<<<dim3(2048), 512, 66560, stream>>>(H, W2T, b2, out);
}

// Round 10
// 687.968 us; speedup vs baseline: 1.0595x; 1.0134x over previous
//
#include <hip/hip_runtime.h>
#include <hip/hip_bf16.h>

#define B_  4
#define T_  256
#define U_  64
#define D_  512
#define INNER_ 512
#define VOCAB_ 2048

// ---------------- types ----------------
typedef __attribute__((ext_vector_type(8))) short short8;   // 8 bf16 (4 VGPRs)
typedef __attribute__((ext_vector_type(4))) float f32x4;

// ---------------- pass 1 (merged): projections + W2 transpose ----------------
// blocks [0,320): proj; blocks [320,1344): w2t. Disjoint data, one dispatch.
__global__ __launch_bounds__(256) void prep_kernel(
    const float* __restrict__ enc, const float* __restrict__ dec,
    const float* __restrict__ W1, const float* __restrict__ b1,
    const float* __restrict__ W2,
    float* __restrict__ encP, float* __restrict__ decPb,
    __hip_bfloat16* __restrict__ W2T) {
  __shared__ float ldsbuf[16 * D_];  // 32 KiB (proj) / reused 32x33 (w2t)
  int tid = threadIdx.x;
  int bidx = blockIdx.x;

  if (bidx < 320) {
    // ---- proj ----
    int ct = bidx & 3;          // 0..3 col tiles of 128
    int rt = bidx >> 2;         // 0..79 row tiles of 16 (64 enc + 16 dec)
    const float* src; float* dst; int kOff; int addB1; int rowBase;
    if (rt < 64) { src = enc; dst = encP; kOff = 0; addB1 = 0; rowBase = rt * 16; }
    else { src = dec; dst = decPb; kOff = D_; addB1 = 1; rowBase = (rt - 64) * 16; }

    float (*As)[D_] = (float(*)[D_])ldsbuf;
    const float4* s4 = (const float4*)(src + (size_t)rowBase * D_);
    float4* a4 = (float4*)(&As[0][0]);
#pragma unroll
    for (int i = 0; i < 8; i++) a4[tid + 256 * i] = s4[tid + 256 * i];
    __syncthreads();

    int colQ = (tid & 31) * 4;
    int col = ct * 128 + colQ;
    int r0 = (tid >> 5) * 2;
    float a00=0,a01=0,a02=0,a03=0, a10=0,a11=0,a12=0,a13=0;
    const float* Wp = W1 + (size_t)kOff * INNER_ + col;
#pragma unroll 4
    for (int k = 0; k < D_; k++) {
      float4 w = *(const float4*)(Wp + (size_t)k * INNER_);
      float e0 = As[r0][k], e1 = As[r0 + 1][k];
      a00 += e0 * w.x; a01 += e0 * w.y; a02 += e0 * w.z; a03 += e0 * w.w;
      a10 += e1 * w.x; a11 += e1 * w.y; a12 += e1 * w.z; a13 += e1 * w.w;
    }
    float4 bb = {0,0,0,0};
    if (addB1) bb = *(const float4*)(b1 + col);
    float4 o0 = {a00 + bb.x, a01 + bb.y, a02 + bb.z, a03 + bb.w};
    float4 o1 = {a10 + bb.x, a11 + bb.y, a12 + bb.z, a13 + bb.w};
    *(float4*)(dst + (size_t)(rowBase + r0) * INNER_ + col) = o0;
    *(float4*)(dst + (size_t)(rowBase + r0 + 1) * INNER_ + col) = o1;
  } else {
    // ---- w2t: W2 (512x2048 f32) -> W2T (2048x512 bf16) ----
    int b = bidx - 320;               // 0..1023
    int vBase = (b & 63) * 32;
    int kBase = (b >> 6) * 32;
    float (*tile)[33] = (float(*)[33])ldsbuf;  // 4.2 KiB
    int tx = tid & 31, ty = tid >> 5; // 32 x 8
#pragma unroll
    for (int i = 0; i < 32; i += 8)
      tile[ty + i][tx] = W2[(size_t)(kBase + ty + i) * VOCAB_ + vBase + tx];
    __syncthreads();
#pragma unroll
    for (int i = 0; i < 32; i += 8)
      W2T[(size_t)(vBase + ty + i) * INNER_ + kBase + tx] = __float2bfloat16(tile[tx][ty + i]);
  }
}

// ---------------- pass 2: hidden H[r][k] = tanh(encP[bt][k] + decPb[b*64+u][k]) ----------------
// grid-stride: 2048 fat blocks instead of 16384 tiny ones (dispatch front-end cost).
__global__ __launch_bounds__(256) void hidden_kernel(
    const float* __restrict__ encP, const float* __restrict__ decPb,
    __hip_bfloat16* __restrict__ H) {
  for (int gid = blockIdx.x * 256 + threadIdx.x; gid < 4194304; gid += 2048 * 256) {
    int k0 = (gid & 63) * 8;
    int r = gid >> 6;            // row in [0, 65536)
    int u = r & 63;
    int bt = r >> 6;             // b*T + t
    int b = bt >> 8;             // T = 256
    const float4* e = (const float4*)(encP + (size_t)bt * 512 + k0);
    const float4* dv = (const float4*)(decPb + (size_t)(b * 64 + u) * 512 + k0);
    float4 e0 = e[0], e1 = e[1];
    float4 d0 = dv[0], d1 = dv[1];
    union { __hip_bfloat16 h[8]; uint4 v; } p;
    p.h[0] = __float2bfloat16(tanhf(e0.x + d0.x));
    p.h[1] = __float2bfloat16(tanhf(e0.y + d0.y));
    p.h[2] = __float2bfloat16(tanhf(e0.z + d0.z));
    p.h[3] = __float2bfloat16(tanhf(e0.w + d0.w));
    p.h[4] = __float2bfloat16(tanhf(e1.x + d1.x));
    p.h[5] = __float2bfloat16(tanhf(e1.y + d1.y));
    p.h[6] = __float2bfloat16(tanhf(e1.z + d1.z));
    p.h[7] = __float2bfloat16(tanhf(e1.w + d1.w));
    *(uint4*)((__hip_bfloat16*)H + (size_t)r * 512 + k0) = p.v;
  }
}

// ---------------- pass 3: main GEMM: out = H(65536x512) * W2T^T + b2 ----------------
// 256x256 tile, BK=64 (halves barrier/waitcnt count vs BK=32: 8 K-steps, 64 MFMA
// per step in two 32-MFMA clusters), 8 waves (2x4), 128 KiB LDS double-buffer,
// counted vmcnt (T4), both-sides XOR swizzle for 128B rows (chunk ^= row&7, T2),
// setprio (T5), bijective XCD swizzle (T1), LDS-repack NT-store epilogue.
__device__ inline void gload_lds16(const void* g, void* l) {
  __builtin_amdgcn_global_load_lds(
      (const __attribute__((address_space(1))) unsigned int*)g,
      (__attribute__((address_space(3))) unsigned int*)l, 16, 0, 0);
}

__global__ __launch_bounds__(512, 1) void joint_gemm(
    const __hip_bfloat16* __restrict__ H, const __hip_bfloat16* __restrict__ W2T,
    const float* __restrict__ b2, float* __restrict__ out) {
  extern __shared__ char smem[];  // 128 KiB: A[2][256][64] bf16 | B[2][256][64] bf16
  int tid = threadIdx.x;
  int lane = tid & 63, wave = tid >> 6;     // 8 waves
  int wm = wave >> 2, wn = wave & 3;        // 2x4 wave grid; per-wave 128x64 output

  // T1: XCD-aware bijective swizzle, nwg = 2048 (divisible by 8)
  int bid = blockIdx.x;
  int wg = (bid & 7) * 256 + (bid >> 3);
  int rt = wg >> 3;          // 0..255 (M tiles of 256)
  int ct = wg & 7;           // 0..7   (N tiles of 256)
  size_t rowBase = (size_t)rt * 256;
  int colBase = ct * 256;

  // ---- staging setup ----
  // Rows are 64 bf16 = 128 B = 8 chunks of 16 B. Swizzle chunk' = chunk ^ (row&7).
  // LDS dest linear (global_load_lds rule); SOURCE pre-swizzled (rule #21).
  // Thread stages row j*64 + (tid>>3), linear chunk tid&7 -> global chunk
  // (tid&7)^((tid>>3)&7). j*64 doesn't touch row bits 0-2, so swz is tid-constant.
  int kswz = ((tid & 7) ^ ((tid >> 3) & 7)) * 8;     // bf16 elem offset in 64-wide k
  int srow = tid >> 3;                               // 0..63
  const __hip_bfloat16* pA = H   + (rowBase + srow) * 512 + kswz;
  const __hip_bfloat16* pB = W2T + (size_t)(colBase + srow) * 512 + kswz;
  char* ldsA = smem;             // [0, 65536): 2 bufs x 32 KiB
  char* ldsB = smem + 65536;     // [65536, 131072)

  // Per STAGE: A 256 rows = 4 issues of 64 rows; B same. 8 loads/thread.
#define STAGE(t, buf) do {                                                    \
    const __hip_bfloat16* ga = pA + (size_t)(t) * 64;                         \
    const __hip_bfloat16* gb = pB + (size_t)(t) * 64;                         \
    char* la = ldsA + (buf) * 32768 + wave * 1024;                            \
    char* lb = ldsB + (buf) * 32768 + wave * 1024;                            \
    _Pragma("unroll")                                                         \
    for (int j = 0; j < 4; j++) {                                             \
      gload_lds16(ga + (size_t)j * 64 * 512, la + j * 8192);                  \
      gload_lds16(gb + (size_t)j * 64 * 512, lb + j * 8192);                  \
    } } while (0)

  // ---- fragment ds_read offsets (swizzle-matched) ----
  // frag row r = base16 + (lane&15); MFMA ks (k=32*ks..+31) needs global chunk
  // g = 4*ks + (lane>>4); swizzled byte = r*128 + ((g ^ (r&7))*16);
  // base16 mult of 16 -> r&7 = lane&7.
  int lo0 = (lane & 15) * 128 + ((((lane >> 4)) ^ (lane & 7)) * 16);       // ks=0
  int lo1 = (lane & 15) * 128 + (((4 + (lane >> 4)) ^ (lane & 7)) * 16);   // ks=1
  int offA = wm * 16384;    // + mi*2048 + lo{0,1}
  int offB = wn * 8192;     // + ni*2048 + lo{0,1}

  // ---- acc init with bias ----
  float bv[4];
#pragma unroll
  for (int ni = 0; ni < 4; ni++) bv[ni] = b2[colBase + wn * 64 + ni * 16 + (lane & 15)];
  f32x4 acc[8][4];
#pragma unroll
  for (int mi = 0; mi < 8; mi++)
#pragma unroll
    for (int ni = 0; ni < 4; ni++)
      acc[mi][ni] = (f32x4){bv[ni], bv[ni], bv[ni], bv[ni]};

  // drain bias loads so vmcnt bookkeeping is exact
  asm volatile("s_waitcnt vmcnt(0)" ::: "memory");
  __builtin_amdgcn_sched_barrier(0);

  // prologue: tiles 0 and 1 in flight (8 loads each -> 16 outstanding)
  STAGE(0, 0);
  STAGE(1, 1);

  // Per K-tile (64 k): vmcnt(8)+barrier (tile t landed) -> ds_read ks0 frags ->
  // 32 MFMA -> ds_read ks1 frags -> lgkmcnt(0)+barrier (buf free) -> restage t+2
  // -> 32 MFMA. Tile t+1's loads stay in flight across everything (T4).
#define KITER(t, buf, VMC, DOSTAGE) do {                                      \
    asm volatile("s_waitcnt vmcnt(" #VMC ")" ::: "memory");                   \
    __builtin_amdgcn_sched_barrier(0);                                        \
    __builtin_amdgcn_s_barrier();                                             \
    __builtin_amdgcn_sched_barrier(0);                                        \
    const char* baA = ldsA + (buf) * 32768 + offA;                            \
    const char* baB = ldsB + (buf) * 32768 + offB;                            \
    short8 afr[8], bfr[4];                                                    \
    _Pragma("unroll") for (int ni = 0; ni < 4; ni++)                          \
      bfr[ni] = *(const short8*)(baB + ni * 2048 + lo0);                      \
    _Pragma("unroll") for (int mi = 0; mi < 8; mi++)                          \
      afr[mi] = *(const short8*)(baA + mi * 2048 + lo0);                      \
    asm volatile("s_waitcnt lgkmcnt(0)" ::: "memory");                        \
    __builtin_amdgcn_sched_barrier(0);                                        \
    __builtin_amdgcn_s_setprio(1);                                            \
    _Pragma("unroll") for (int mi = 0; mi < 8; mi++)                          \
      _Pragma("unroll") for (int ni = 0; ni < 4; ni++)                        \
        acc[mi][ni] = __builtin_amdgcn_mfma_f32_16x16x32_bf16(                \
            afr[mi], bfr[ni], acc[mi][ni], 0, 0, 0);                          \
    __builtin_amdgcn_s_setprio(0);                                            \
    _Pragma("unroll") for (int ni = 0; ni < 4; ni++)                          \
      bfr[ni] = *(const short8*)(baB + ni * 2048 + lo1);                      \
    _Pragma("unroll") for (int mi = 0; mi < 8; mi++)                          \
      afr[mi] = *(const short8*)(baA + mi * 2048 + lo1);                      \
    asm volatile("s_waitcnt lgkmcnt(0)" ::: "memory");                        \
    __builtin_amdgcn_sched_barrier(0);                                        \
    __builtin_amdgcn_s_barrier();                                             \
    __builtin_amdgcn_sched_barrier(0);                                        \
    if (DOSTAGE) { STAGE((t) + 2, (buf)); }                                   \
    __builtin_amdgcn_sched_barrier(0);                                        \
    __builtin_amdgcn_s_setprio(1);                                            \
    _Pragma("unroll") for (int mi = 0; mi < 8; mi++)                          \
      _Pragma("unroll") for (int ni = 0; ni < 4; ni++)                        \
        acc[mi][ni] = __builtin_amdgcn_mfma_f32_16x16x32_bf16(                \
            afr[mi], bfr[ni], acc[mi][ni], 0, 0, 0);                          \
    __builtin_amdgcn_s_setprio(0);                                            \
  } while (0)

#pragma unroll
  for (int t = 0; t < 6; ++t) KITER(t, (t & 1), 8, 1);
  KITER(6, 0, 8, 0);
  KITER(7, 1, 0, 0);
#undef KITER
#undef STAGE

  // ---- epilogue: LDS repack -> coalesced 1 KiB/wave NON-TEMPORAL dwordx4 stores ----
  // 4 rounds of a 64x256 f32 panel (stride 260 dwords: 16B-aligned rows, 2-way banks).
  // Round r = tile rows [r*64,+64): waves with wm==r>>1 write acc[(r&1)*4..+3][*];
  // then all 512 threads stream the panel (64 lanes x 16 B = one 1 KiB row).
  {
    float* lp = (float*)smem;
    float* outBase = out + rowBase * VOCAB_ + colBase;
#pragma unroll
    for (int r = 0; r < 4; r++) {
      __syncthreads();                       // prev round's reads complete
      if (wm == (r >> 1)) {
        int mih = (r & 1) * 4;
#pragma unroll
        for (int q = 0; q < 4; q++) {
          int lrow0 = q * 16 + ((lane >> 4) << 2);
#pragma unroll
          for (int ni = 0; ni < 4; ni++) {
            int col = wn * 64 + ni * 16 + (lane & 15);
            f32x4 v = acc[mih + q][ni];
#pragma unroll
            for (int j = 0; j < 4; j++)
              lp[(lrow0 + j) * 260 + col] = v[j];
          }
        }
      }
      __syncthreads();                       // panel ready
#pragma unroll
      for (int i = 0; i < 8; i++) {
        int c = tid + 512 * i;               // [0,4096): row = c>>6, chunk = c&63
        int row = c >> 6, cc = c & 63;
        f32x4 v = *(const f32x4*)(lp + row * 260 + cc * 4);
        __builtin_nontemporal_store(
            v, (f32x4*)(outBase + (size_t)(r * 64 + row) * VOCAB_ + cc * 4));
      }
    }
  }
}

extern "C" void kernel_launch(void* const* d_in, const int* in_sizes, int n_in,
                              void* d_out, int out_size, void* d_ws, size_t ws_size,
                              hipStream_t stream) {
  const float* enc = (const float*)d_in[0];
  const float* dec = (const float*)d_in[1];
  const float* W1  = (const float*)d_in[2];
  const float* b1  = (const float*)d_in[3];
  const float* W2  = (const float*)d_in[4];
  const float* b2  = (const float*)d_in[5];
  float* out = (float*)d_out;

  char* ws = (char*)d_ws;
  float* encP  = (float*)ws;                                   // 1024*512*4 = 2 MiB
  float* decPb = (float*)(ws + (2u << 20));                    // 256*512*4 = 512 KiB
  __hip_bfloat16* W2T = (__hip_bfloat16*)(ws + (2u << 20) + (512u << 10));          // 2 MiB
  __hip_bfloat16* H   = (__hip_bfloat16*)(ws + (2u << 20) + (512u << 10) + (2u << 20)); // 64 MiB

  static int smem_set = 0;
  if (!smem_set) {
    (void)hipFuncSetAttribute((const void*)joint_gemm,
                              hipFuncAttributeMaxDynamicSharedMemorySize, 131072);
    smem_set = 1;
  }

  prep_kernel<<<dim3(1344), 256, 0, stream>>>(enc, dec, W1, b1, W2, encP, decPb, W2T);
  hidden_kernel<<<2048, 256, 0, stream>>>(encP, decPb, H);
  joint_gemm<<<dim3(2048), 512, 131072, stream>>>(H, W2T, b2, out);
}